// Round 4
// baseline (492.955 us; speedup 1.0000x reference)
//
#include <hip/hip_runtime.h>
#include <cmath>

#define IN_DIM 64
#define NBLK   128     // blocks for bin-count / bin-place (power of 2; shift 7)
#define BSH    6       // 64 nodes per bucket

// ---- fused: node scores (blocks [0,scoreBlocks)) + coarse bucket count -----
__global__ void scores_and_count_kernel(const float* __restrict__ h,
                                        const float* __restrict__ d,
                                        const float* __restrict__ gate_w,
                                        const float* __restrict__ gate_b,
                                        float2* __restrict__ pairD,
                                        float2* __restrict__ pairS,
                                        const int* __restrict__ dst,
                                        int* __restrict__ counts,   // [NBLK][NB]
                                        int n_nodes, int n_edges, int NB,
                                        int scoreBlocks) {
    extern __shared__ int cnt[];                  // NB ints (count role only)
    if ((int)blockIdx.x < scoreBlocks) {
        int gid  = blockIdx.x * blockDim.x + threadIdx.x;
        int node = gid >> 6;
        int lane = threadIdx.x & 63;
        if (node >= n_nodes) return;
        float hv = h[node * IN_DIM + lane];
        float pd = hv * gate_w[lane];             // w_dst = gate_w[:64]
        float ps = hv * gate_w[IN_DIM + lane];    // w_src = gate_w[64:]
        #pragma unroll
        for (int off = 32; off > 0; off >>= 1) {
            pd += __shfl_xor(pd, off, 64);
            ps += __shfl_xor(ps, off, 64);
        }
        if (lane == 0) {
            float dv = d[node];
            pairD[node] = make_float2(pd + gate_b[0], dv);
            pairS[node] = make_float2(ps, dv);
        }
    } else {
        int bk  = blockIdx.x - scoreBlocks;       // 0..NBLK-1
        int tid = threadIdx.x;
        for (int b = tid; b < NB; b += blockDim.x) cnt[b] = 0;
        __syncthreads();
        int slice = (n_edges + NBLK - 1) / NBLK;
        int e0 = bk * slice;
        int e1 = min(e0 + slice, n_edges);
        for (int e = e0 + tid; e < e1; e += blockDim.x)
            atomicAdd(&cnt[dst[e] >> BSH], 1);
        __syncthreads();
        for (int b = tid; b < NB; b += blockDim.x)
            counts[bk * NB + b] = cnt[b];         // coalesced
    }
}

// ---- single-block exclusive scan over bucket-major (b, block) order --------
__global__ void scan_kernel(const int* __restrict__ counts,  // [NBLK][NB]
                            int* __restrict__ scanout,       // [NB*NBLK]
                            int total, int NB) {
    __shared__ int wsum[16];
    __shared__ int wpre[16];
    __shared__ int carry;
    int tid = threadIdx.x, lane = tid & 63, w = tid >> 6;
    if (tid == 0) carry = 0;
    __syncthreads();
    for (int base = 0; base < total; base += 1024) {
        int i = base + tid;
        int orig = 0;
        if (i < total) orig = counts[(i & (NBLK - 1)) * NB + (i >> 7)];
        int v = orig;
        #pragma unroll
        for (int dd = 1; dd < 64; dd <<= 1) {
            int t = __shfl_up(v, dd, 64);
            if (lane >= dd) v += t;
        }
        if (lane == 63) wsum[w] = v;
        __syncthreads();
        if (tid == 0) {
            int run = 0;
            for (int j = 0; j < 16; ++j) { wpre[j] = run; run += wsum[j]; }
            wsum[0] = run;                        // stash block total
        }
        __syncthreads();
        if (i < total) scanout[i] = (v - orig) + wpre[w] + carry;
        __syncthreads();
        if (tid == 0) carry += wsum[0];
        __syncthreads();
    }
}

// ---- place edges into per-(bucket,block) contiguous runs -------------------
__global__ void bin_place_kernel(const int* __restrict__ src,
                                 const int* __restrict__ dst,
                                 const int* __restrict__ scanout,  // [NB*NBLK]
                                 int* __restrict__ entries,
                                 int n_edges, int NB) {
    extern __shared__ int smem[];
    int* base = smem;          // NB
    int* cur  = smem + NB;     // NB
    int bk  = blockIdx.x;
    int tid = threadIdx.x;
    for (int b = tid; b < NB; b += blockDim.x) {
        base[b] = scanout[b * NBLK + bk];
        cur[b]  = 0;
    }
    __syncthreads();
    int slice = (n_edges + NBLK - 1) / NBLK;
    int e0 = bk * slice;
    int e1 = min(e0 + slice, n_edges);
    for (int e = e0 + tid; e < e1; e += blockDim.x) {
        int t = dst[e];
        int b = t >> BSH;
        int sl = atomicAdd(&cur[b], 1);
        entries[base[b] + sl] = ((t & 63) << 17) | src[e];
    }
}

// ---- fused demux + gather: one workgroup per 64-node bucket ----------------
__global__ void bucket_gather_kernel(const float* __restrict__ h,
                                     const float2* __restrict__ pairD,
                                     const float2* __restrict__ pairS,
                                     const int* __restrict__ scanout,
                                     const int* __restrict__ entries,
                                     float* __restrict__ z,
                                     int n_nodes, int n_edges, int NB) {
    __shared__ float  acc[64][65];     // +1 pad: spreads banks across rows
    __shared__ float2 pds[64];
    int b    = blockIdx.x;
    int tid  = threadIdx.x;            // 256 threads = 4 waves
    int lane = tid & 63;
    int w    = tid >> 6;
    int slot = lane >> 4;              // 4 edges per wave-iteration
    int quad = lane & 15;              // float4 chunk of the h row

    int node0 = b << BSH;
    for (int i = tid; i < 64 * 65; i += 256) ((float*)acc)[i] = 0.f;
    if (tid < 64)
        pds[tid] = (node0 + tid < n_nodes) ? pairD[node0 + tid]
                                           : make_float2(0.f, 0.f);
    int beg = scanout[b * NBLK];
    int end = (b + 1 < NB) ? scanout[(b + 1) * NBLK] : n_edges;
    __syncthreads();

    for (int g = beg + w * 4; g < end; g += 16) {
        int j = g + slot;
        bool valid = (j < end);
        int e  = valid ? entries[j] : 0;
        int s  = e & 0x1FFFF;
        int dl = e >> 17;
        float2 ps = pairS[s];                        // 8B broadcast per slot
        float c = valid ? tanhf(pds[dl].x + ps.x) * ps.y : 0.f;
        const float4 hv = *reinterpret_cast<const float4*>(
            &h[(size_t)s * IN_DIM + quad * 4]);
        if (valid) {
            float* row = &acc[dl][quad * 4];
            atomicAdd(&row[0], hv.x * c);
            atomicAdd(&row[1], hv.y * c);
            atomicAdd(&row[2], hv.z * c);
            atomicAdd(&row[3], hv.w * c);
        }
    }
    __syncthreads();

    // write out: 16 rows per wave, coalesced 256B per row, fold in d[dst]
    for (int r = w; r < 64; r += 4) {
        int node = node0 + r;
        if (node < n_nodes)
            z[(size_t)node * IN_DIM + lane] = acc[r][lane] * pds[r].y;
    }
}

// ---- fallback (atomic push) if workspace too small / NB too big ------------
__global__ void node_scores_kernel(const float* __restrict__ h,
                                   const float* __restrict__ d,
                                   const float* __restrict__ gate_w,
                                   const float* __restrict__ gate_b,
                                   float2* __restrict__ pairD,
                                   float2* __restrict__ pairS,
                                   int n_nodes) {
    int gid  = blockIdx.x * blockDim.x + threadIdx.x;
    int node = gid >> 6;
    int lane = threadIdx.x & 63;
    if (node >= n_nodes) return;
    float hv = h[node * IN_DIM + lane];
    float pd = hv * gate_w[lane];
    float ps = hv * gate_w[IN_DIM + lane];
    #pragma unroll
    for (int off = 32; off > 0; off >>= 1) {
        pd += __shfl_xor(pd, off, 64);
        ps += __shfl_xor(ps, off, 64);
    }
    if (lane == 0) {
        float dv = d[node];
        pairD[node] = make_float2(pd + gate_b[0], dv);
        pairS[node] = make_float2(ps, dv);
    }
}

__global__ void edge_scatter_atomic_kernel(const float* __restrict__ h,
                                           const int* __restrict__ src,
                                           const int* __restrict__ dst,
                                           const float2* __restrict__ pairD,
                                           const float2* __restrict__ pairS,
                                           float* __restrict__ z,
                                           int n_edges) {
    int gid  = blockIdx.x * blockDim.x + threadIdx.x;
    int e    = gid >> 6;
    int lane = threadIdx.x & 63;
    if (e >= n_edges) return;
    int s = src[e];
    int t = dst[e];
    float2 pt = pairD[t];
    float2 ps = pairS[s];
    float c = tanhf(pt.x + ps.x) * pt.y * ps.y;
    atomicAdd(&z[t * IN_DIM + lane], h[s * IN_DIM + lane] * c);
}

extern "C" void kernel_launch(void* const* d_in, const int* in_sizes, int n_in,
                              void* d_out, int out_size, void* d_ws, size_t ws_size,
                              hipStream_t stream) {
    const float* h      = (const float*)d_in[0];
    const float* d      = (const float*)d_in[1];
    const int*   src    = (const int*)d_in[2];
    const int*   dst    = (const int*)d_in[3];
    const float* gate_w = (const float*)d_in[4];
    const float* gate_b = (const float*)d_in[5];

    const int n_nodes = in_sizes[1];
    const int n_edges = in_sizes[2];
    float* z = (float*)d_out;

    const int NB = (n_nodes + 63) >> BSH;   // 64-node buckets

    // workspace: pairD, pairS, entries, counts, scanout
    size_t need = (size_t)n_nodes * 2 * sizeof(float2)
                + (size_t)n_edges * sizeof(int)
                + (size_t)2 * NB * NBLK * sizeof(int);

    // src must fit 17 bits for the packed entry format
    if (ws_size < need || NB > 8192 || n_nodes > (1 << 17)) {
        float2* pairD = (float2*)d_ws;
        float2* pairS = pairD + n_nodes;
        hipMemsetAsync(z, 0, (size_t)out_size * sizeof(float), stream);
        {
            int total = n_nodes * 64, threads = 256;
            node_scores_kernel<<<(total + threads - 1) / threads, threads, 0, stream>>>(
                h, d, gate_w, gate_b, pairD, pairS, n_nodes);
        }
        {
            long long total = (long long)n_edges * 64;
            int threads = 256;
            edge_scatter_atomic_kernel<<<(int)((total + threads - 1) / threads), threads, 0, stream>>>(
                h, src, dst, pairD, pairS, z, n_edges);
        }
        return;
    }

    float2* pairD   = (float2*)d_ws;
    float2* pairS   = pairD + n_nodes;
    int*    entries = (int*)(pairS + n_nodes);
    int*    counts  = entries + n_edges;        // [NBLK][NB]
    int*    scanout = counts + NB * NBLK;       // [NB*NBLK], bucket-major

    const int scoreBlocks = (n_nodes * 64 + 255) / 256;

    // 1) node scores + per-block bucket histogram (independent roles)
    scores_and_count_kernel<<<scoreBlocks + NBLK, 256, NB * sizeof(int), stream>>>(
        h, d, gate_w, gate_b, pairD, pairS, dst, counts,
        n_nodes, n_edges, NB, scoreBlocks);

    // 2) exclusive scan over (bucket, block) in bucket-major order
    scan_kernel<<<1, 1024, 0, stream>>>(counts, scanout, NB * NBLK, NB);

    // 3) place edges into per-(bucket,block) contiguous runs
    bin_place_kernel<<<NBLK, 256, 2 * NB * sizeof(int), stream>>>(
        src, dst, scanout, entries, n_edges, NB);

    // 4) fused demux + gather + z write (one workgroup per bucket)
    bucket_gather_kernel<<<NB, 256, 0, stream>>>(
        h, pairD, pairS, scanout, entries, z, n_nodes, n_edges, NB);
}

// Round 5
// 94.834 us; speedup vs baseline: 5.1981x; 5.1981x over previous
//
#include <hip/hip_runtime.h>
#include <cmath>

#define IN_DIM 64
#define NBLK   128     // blocks for bin-count / bin-place (must be 128: 2 waves scan)
#define BSH    6       // 64 nodes per bucket

// ---- K1 fused: node scores (blocks [0,scoreBlocks)) + per-block bucket count
__global__ void scores_and_count_kernel(const float* __restrict__ h,
                                        const float* __restrict__ d,
                                        const float* __restrict__ gate_w,
                                        const float* __restrict__ gate_b,
                                        float2* __restrict__ pairD,
                                        float2* __restrict__ pairS,
                                        const int* __restrict__ dst,
                                        int* __restrict__ counts,   // [NBLK][NB]
                                        int n_nodes, int n_edges, int NB,
                                        int scoreBlocks) {
    extern __shared__ int cnt[];                  // NB ints (count role only)
    if ((int)blockIdx.x < scoreBlocks) {
        int gid  = blockIdx.x * blockDim.x + threadIdx.x;
        int node = gid >> 6;
        int lane = threadIdx.x & 63;
        if (node >= n_nodes) return;
        float hv = h[node * IN_DIM + lane];
        float pd = hv * gate_w[lane];             // w_dst = gate_w[:64]
        float ps = hv * gate_w[IN_DIM + lane];    // w_src = gate_w[64:]
        #pragma unroll
        for (int off = 32; off > 0; off >>= 1) {
            pd += __shfl_xor(pd, off, 64);
            ps += __shfl_xor(ps, off, 64);
        }
        if (lane == 0) {
            float dv = d[node];
            pairD[node] = make_float2(pd + gate_b[0], dv);
            pairS[node] = make_float2(ps, dv);
        }
    } else {
        int bk  = blockIdx.x - scoreBlocks;       // 0..NBLK-1
        int tid = threadIdx.x;
        for (int b = tid; b < NB; b += blockDim.x) cnt[b] = 0;
        __syncthreads();
        int slice = (n_edges + NBLK - 1) / NBLK;
        int e0 = bk * slice;
        int e1 = min(e0 + slice, n_edges);
        for (int e = e0 + tid; e < e1; e += blockDim.x)
            atomicAdd(&cnt[dst[e] >> BSH], 1);
        __syncthreads();
        for (int b = tid; b < NB; b += blockDim.x)
            counts[bk * NB + b] = cnt[b];         // coalesced
    }
}

// ---- K2: per-bucket exclusive scan over the NBLK block counts --------------
__global__ void bucket_block_scan_kernel(const int* __restrict__ counts, // [NBLK][NB]
                                         int* __restrict__ within,      // [NB][NBLK]
                                         int* __restrict__ btot,        // [NB]
                                         int NB) {
    __shared__ int w0sum;
    int b   = blockIdx.x;
    int tid = threadIdx.x;                        // NBLK = 128 threads, 2 waves
    int v = counts[tid * NB + b];                 // strided read, L2-hot
    int incl = v;
    #pragma unroll
    for (int dd = 1; dd < 64; dd <<= 1) {
        int t = __shfl_up(incl, dd, 64);
        if ((tid & 63) >= dd) incl += t;
    }
    if (tid == 63) w0sum = incl;
    __syncthreads();
    if (tid >= 64) incl += w0sum;
    within[b * NBLK + tid] = incl - v;            // exclusive, coalesced write
    if (tid == NBLK - 1) btot[b] = incl;
}

// ---- K2b: single-block exclusive scan of bucket totals ---------------------
__global__ void bucket_base_scan_kernel(const int* __restrict__ btot,
                                        int* __restrict__ bucketBase,  // [NB+1]
                                        int* __restrict__ off,         // [n_nodes+1]
                                        int NB, int n_nodes, int n_edges) {
    __shared__ int wsum[16];
    __shared__ int wpre[16];
    int tid = threadIdx.x;                        // 1024
    int lane = tid & 63, w = tid >> 6;
    int v = (tid < NB) ? btot[tid] : 0;
    int incl = v;
    #pragma unroll
    for (int dd = 1; dd < 64; dd <<= 1) {
        int t = __shfl_up(incl, dd, 64);
        if (lane >= dd) incl += t;
    }
    if (lane == 63) wsum[w] = incl;
    __syncthreads();
    if (tid == 0) {
        int run = 0;
        for (int j = 0; j < 16; ++j) { wpre[j] = run; run += wsum[j]; }
    }
    __syncthreads();
    int excl = incl - v + wpre[w];
    if (tid < NB) bucketBase[tid] = excl;
    if (tid == 0) { bucketBase[NB] = n_edges; off[n_nodes] = n_edges; }
}

// ---- K3: place edges into per-(bucket,block) contiguous runs ---------------
__global__ void bin_place_kernel(const int* __restrict__ src,
                                 const int* __restrict__ dst,
                                 const int* __restrict__ bucketBase,
                                 const int* __restrict__ within,    // [NB][NBLK]
                                 int* __restrict__ entries,
                                 int n_edges, int NB) {
    extern __shared__ int smem[];
    int* base = smem;          // NB
    int* cur  = smem + NB;     // NB
    int bk  = blockIdx.x;
    int tid = threadIdx.x;
    for (int b = tid; b < NB; b += blockDim.x) {
        base[b] = bucketBase[b] + within[b * NBLK + bk];
        cur[b]  = 0;
    }
    __syncthreads();
    int slice = (n_edges + NBLK - 1) / NBLK;
    int e0 = bk * slice;
    int e1 = min(e0 + slice, n_edges);
    for (int e = e0 + tid; e < e1; e += blockDim.x) {
        int t = dst[e];
        int b = t >> BSH;
        int sl = atomicAdd(&cur[b], 1);
        entries[base[b] + sl] = ((t & 63) << 17) | src[e];   // block-local lines
    }
}

// ---- K4: within-bucket counting sort -> per-node CSR (pack, off) -----------
__global__ void bucket_sort_kernel(const int* __restrict__ entries,
                                   const int* __restrict__ bucketBase,
                                   int* __restrict__ pack,
                                   int* __restrict__ off,
                                   int n_nodes, int NB) {
    __shared__ int cnt[64];
    __shared__ int cur[64];
    int b   = blockIdx.x;
    int tid = threadIdx.x;                        // 256
    int beg = bucketBase[b];
    int end = bucketBase[b + 1];
    if (tid < 64) cnt[tid] = 0;
    __syncthreads();
    for (int j = beg + tid; j < end; j += 256)
        atomicAdd(&cnt[entries[j] >> 17], 1);
    __syncthreads();
    if (tid < 64) {                               // wave 0: scan 64 bins
        int v = cnt[tid];
        int incl = v;
        #pragma unroll
        for (int dd = 1; dd < 64; dd <<= 1) {
            int t = __shfl_up(incl, dd, 64);
            if (tid >= dd) incl += t;
        }
        int excl = incl - v;
        cur[tid] = excl;
        int node = (b << BSH) + tid;
        if (node < n_nodes) off[node] = beg + excl;
    }
    __syncthreads();
    for (int j = beg + tid; j < end; j += 256) {
        int e = entries[j];
        int pos = beg + atomicAdd(&cur[e >> 17], 1);
        pack[pos] = e & 0x1FFFF;                  // writes stay in bucket region
    }
}

// ---- K5: pull-reduce, wave per node, 4 edge-slots x float4 (r3-proven) -----
__global__ void gather_kernel(const float* __restrict__ h,
                              const float2* __restrict__ pairD,
                              const float2* __restrict__ pairS,
                              const int* __restrict__ off,
                              const int* __restrict__ pack,
                              float* __restrict__ z,
                              int n_nodes) {
    int gid  = blockIdx.x * blockDim.x + threadIdx.x;
    int node = gid >> 6;
    int lane = threadIdx.x & 63;
    if (node >= n_nodes) return;

    int slot = lane >> 4;      // 0..3 : which edge of the group of 4
    int quad = lane & 15;      // feature quad: floats [quad*4, quad*4+4)

    int beg = off[node];
    int end = off[node + 1];
    float2 pd = pairD[node];   // (sD+b, d[t]) — wave-uniform

    float4 acc = make_float4(0.f, 0.f, 0.f, 0.f);
    for (int base = beg; base < end; base += 4) {
        int j  = base + slot;
        bool v = (j < end);
        int  s = v ? pack[j] : 0;
        float2 ps = pairS[s];                       // (sS, d[s]) broadcast 8B
        float c = v ? tanhf(pd.x + ps.x) * ps.y : 0.f;
        const float4 hv = *reinterpret_cast<const float4*>(
            &h[(size_t)s * IN_DIM + quad * 4]);
        acc.x = fmaf(hv.x, c, acc.x);
        acc.y = fmaf(hv.y, c, acc.y);
        acc.z = fmaf(hv.z, c, acc.z);
        acc.w = fmaf(hv.w, c, acc.w);
    }

    acc.x += __shfl_xor(acc.x, 16, 64);
    acc.y += __shfl_xor(acc.y, 16, 64);
    acc.z += __shfl_xor(acc.z, 16, 64);
    acc.w += __shfl_xor(acc.w, 16, 64);
    acc.x += __shfl_xor(acc.x, 32, 64);
    acc.y += __shfl_xor(acc.y, 32, 64);
    acc.z += __shfl_xor(acc.z, 32, 64);
    acc.w += __shfl_xor(acc.w, 32, 64);

    if (slot == 0) {
        acc.x *= pd.y; acc.y *= pd.y; acc.z *= pd.y; acc.w *= pd.y;  // * d[t]
        *reinterpret_cast<float4*>(&z[(size_t)node * IN_DIM + quad * 4]) = acc;
    }
}

// ---- fallback (atomic push) ------------------------------------------------
__global__ void node_scores_kernel(const float* __restrict__ h,
                                   const float* __restrict__ d,
                                   const float* __restrict__ gate_w,
                                   const float* __restrict__ gate_b,
                                   float2* __restrict__ pairD,
                                   float2* __restrict__ pairS,
                                   int n_nodes) {
    int gid  = blockIdx.x * blockDim.x + threadIdx.x;
    int node = gid >> 6;
    int lane = threadIdx.x & 63;
    if (node >= n_nodes) return;
    float hv = h[node * IN_DIM + lane];
    float pd = hv * gate_w[lane];
    float ps = hv * gate_w[IN_DIM + lane];
    #pragma unroll
    for (int off = 32; off > 0; off >>= 1) {
        pd += __shfl_xor(pd, off, 64);
        ps += __shfl_xor(ps, off, 64);
    }
    if (lane == 0) {
        float dv = d[node];
        pairD[node] = make_float2(pd + gate_b[0], dv);
        pairS[node] = make_float2(ps, dv);
    }
}

__global__ void edge_scatter_atomic_kernel(const float* __restrict__ h,
                                           const int* __restrict__ src,
                                           const int* __restrict__ dst,
                                           const float2* __restrict__ pairD,
                                           const float2* __restrict__ pairS,
                                           float* __restrict__ z,
                                           int n_edges) {
    int gid  = blockIdx.x * blockDim.x + threadIdx.x;
    int e    = gid >> 6;
    int lane = threadIdx.x & 63;
    if (e >= n_edges) return;
    int s = src[e];
    int t = dst[e];
    float2 pt = pairD[t];
    float2 ps = pairS[s];
    float c = tanhf(pt.x + ps.x) * pt.y * ps.y;
    atomicAdd(&z[t * IN_DIM + lane], h[s * IN_DIM + lane] * c);
}

extern "C" void kernel_launch(void* const* d_in, const int* in_sizes, int n_in,
                              void* d_out, int out_size, void* d_ws, size_t ws_size,
                              hipStream_t stream) {
    const float* h      = (const float*)d_in[0];
    const float* d      = (const float*)d_in[1];
    const int*   src    = (const int*)d_in[2];
    const int*   dst    = (const int*)d_in[3];
    const float* gate_w = (const float*)d_in[4];
    const float* gate_b = (const float*)d_in[5];

    const int n_nodes = in_sizes[1];
    const int n_edges = in_sizes[2];
    float* z = (float*)d_out;

    const int NB = (n_nodes + 63) >> BSH;   // 64-node buckets (782)

    // ws layout: pairD, pairS, pack, entries, counts, within, btot, bucketBase, off
    size_t need = (size_t)n_nodes * 2 * sizeof(float2)
                + (size_t)n_edges * 2 * sizeof(int)
                + (size_t)(2 * NB * NBLK + 2 * NB + 1 + n_nodes + 1) * sizeof(int);

    if (ws_size < need || NB > 1024 || n_nodes > (1 << 17)) {
        float2* pairD = (float2*)d_ws;
        float2* pairS = pairD + n_nodes;
        hipMemsetAsync(z, 0, (size_t)out_size * sizeof(float), stream);
        {
            int total = n_nodes * 64, threads = 256;
            node_scores_kernel<<<(total + threads - 1) / threads, threads, 0, stream>>>(
                h, d, gate_w, gate_b, pairD, pairS, n_nodes);
        }
        {
            long long total = (long long)n_edges * 64;
            int threads = 256;
            edge_scatter_atomic_kernel<<<(int)((total + threads - 1) / threads), threads, 0, stream>>>(
                h, src, dst, pairD, pairS, z, n_edges);
        }
        return;
    }

    float2* pairD      = (float2*)d_ws;
    float2* pairS      = pairD + n_nodes;
    int*    pack       = (int*)(pairS + n_nodes);   // n_edges
    int*    entries    = pack + n_edges;            // n_edges
    int*    counts     = entries + n_edges;         // [NBLK][NB]
    int*    within     = counts + NBLK * NB;        // [NB][NBLK]
    int*    btot       = within + NB * NBLK;        // NB
    int*    bucketBase = btot + NB;                 // NB+1
    int*    off        = bucketBase + NB + 1;       // n_nodes+1

    const int scoreBlocks = (n_nodes * 64 + 255) / 256;

    // K1: node scores + per-block bucket histogram
    scores_and_count_kernel<<<scoreBlocks + NBLK, 256, NB * sizeof(int), stream>>>(
        h, d, gate_w, gate_b, pairD, pairS, dst, counts,
        n_nodes, n_edges, NB, scoreBlocks);

    // K2: per-bucket scan across blocks
    bucket_block_scan_kernel<<<NB, NBLK, 0, stream>>>(counts, within, btot, NB);

    // K2b: scan bucket totals -> bucketBase; off[n]=n_edges
    bucket_base_scan_kernel<<<1, 1024, 0, stream>>>(
        btot, bucketBase, off, NB, n_nodes, n_edges);

    // K3: place edges into per-(bucket,block) contiguous runs
    bin_place_kernel<<<NBLK, 256, 2 * NB * sizeof(int), stream>>>(
        src, dst, bucketBase, within, entries, n_edges, NB);

    // K4: within-bucket counting sort -> per-node CSR (pack) + off
    bucket_sort_kernel<<<NB, 256, 0, stream>>>(
        entries, bucketBase, pack, off, n_nodes, NB);

    // K5: pull-reduce gather (wave per node), writes z exactly once
    {
        long long total = (long long)n_nodes * 64;
        gather_kernel<<<(int)((total + 255) / 256), 256, 0, stream>>>(
            h, pairD, pairS, off, pack, z, n_nodes);
    }
}

// Round 6
// 85.741 us; speedup vs baseline: 5.7493x; 1.1060x over previous
//
#include <hip/hip_runtime.h>
#include <cmath>

#define IN_DIM 64
#define NBLK   128     // blocks for bin-count / bin-place (must be 128: 2 waves scan)
#define BSH    6       // 64 nodes per bucket

// fast tanh: 1 - 2/(e^{2x}+1); saturates correctly (+inf->1, -inf->-1)
__device__ __forceinline__ float fast_tanh(float x) {
    return 1.0f - __fdividef(2.0f, __expf(2.0f * x) + 1.0f);
}

// ---- K1 fused: node scores (blocks [0,scoreBlocks)) + per-block bucket count
__global__ void scores_and_count_kernel(const float* __restrict__ h,
                                        const float* __restrict__ d,
                                        const float* __restrict__ gate_w,
                                        const float* __restrict__ gate_b,
                                        float2* __restrict__ pairD,
                                        float2* __restrict__ pairS,
                                        const int* __restrict__ dst,
                                        int* __restrict__ counts,   // [NBLK][NB]
                                        int n_nodes, int n_edges, int NB,
                                        int scoreBlocks) {
    extern __shared__ int cnt[];                  // NB ints (count role only)
    if ((int)blockIdx.x < scoreBlocks) {
        int gid  = blockIdx.x * blockDim.x + threadIdx.x;
        int node = gid >> 6;
        int lane = threadIdx.x & 63;
        if (node >= n_nodes) return;
        float hv = h[node * IN_DIM + lane];
        float pd = hv * gate_w[lane];             // w_dst = gate_w[:64]
        float ps = hv * gate_w[IN_DIM + lane];    // w_src = gate_w[64:]
        #pragma unroll
        for (int off = 32; off > 0; off >>= 1) {
            pd += __shfl_xor(pd, off, 64);
            ps += __shfl_xor(ps, off, 64);
        }
        if (lane == 0) {
            float dv = d[node];
            pairD[node] = make_float2(pd + gate_b[0], dv);
            pairS[node] = make_float2(ps, dv);
        }
    } else {
        int bk  = blockIdx.x - scoreBlocks;       // 0..NBLK-1
        int tid = threadIdx.x;
        for (int b = tid; b < NB; b += blockDim.x) cnt[b] = 0;
        __syncthreads();
        int slice = (n_edges + NBLK - 1) / NBLK;
        int e0 = bk * slice;
        int e1 = min(e0 + slice, n_edges);
        for (int e = e0 + tid; e < e1; e += blockDim.x)
            atomicAdd(&cnt[dst[e] >> BSH], 1);
        __syncthreads();
        for (int b = tid; b < NB; b += blockDim.x)
            counts[bk * NB + b] = cnt[b];         // coalesced
    }
}

// ---- K2: per-bucket exclusive scan over the NBLK block counts --------------
__global__ void bucket_block_scan_kernel(const int* __restrict__ counts, // [NBLK][NB]
                                         int* __restrict__ within,      // [NB][NBLK]
                                         int* __restrict__ btot,        // [NB]
                                         int NB) {
    __shared__ int w0sum;
    int b   = blockIdx.x;
    int tid = threadIdx.x;                        // NBLK = 128 threads, 2 waves
    int v = counts[tid * NB + b];                 // strided read, L2-hot
    int incl = v;
    #pragma unroll
    for (int dd = 1; dd < 64; dd <<= 1) {
        int t = __shfl_up(incl, dd, 64);
        if ((tid & 63) >= dd) incl += t;
    }
    if (tid == 63) w0sum = incl;
    __syncthreads();
    if (tid >= 64) incl += w0sum;
    within[b * NBLK + tid] = incl - v;            // exclusive, coalesced write
    if (tid == NBLK - 1) btot[b] = incl;
}

// ---- K2b: single-block exclusive scan of bucket totals ---------------------
__global__ void bucket_base_scan_kernel(const int* __restrict__ btot,
                                        int* __restrict__ bucketBase,  // [NB+1]
                                        int* __restrict__ off,         // [n_nodes+1]
                                        int NB, int n_nodes, int n_edges) {
    __shared__ int wsum[16];
    __shared__ int wpre[16];
    int tid = threadIdx.x;                        // 1024
    int lane = tid & 63, w = tid >> 6;
    int v = (tid < NB) ? btot[tid] : 0;
    int incl = v;
    #pragma unroll
    for (int dd = 1; dd < 64; dd <<= 1) {
        int t = __shfl_up(incl, dd, 64);
        if (lane >= dd) incl += t;
    }
    if (lane == 63) wsum[w] = incl;
    __syncthreads();
    if (tid == 0) {
        int run = 0;
        for (int j = 0; j < 16; ++j) { wpre[j] = run; run += wsum[j]; }
    }
    __syncthreads();
    int excl = incl - v + wpre[w];
    if (tid < NB) bucketBase[tid] = excl;
    if (tid == 0) { bucketBase[NB] = n_edges; off[n_nodes] = n_edges; }
}

// ---- K3: place edges into per-(bucket,block) contiguous runs ---------------
__global__ void bin_place_kernel(const int* __restrict__ src,
                                 const int* __restrict__ dst,
                                 const int* __restrict__ bucketBase,
                                 const int* __restrict__ within,    // [NB][NBLK]
                                 int* __restrict__ entries,
                                 int n_edges, int NB) {
    extern __shared__ int smem[];
    int* base = smem;          // NB
    int* cur  = smem + NB;     // NB
    int bk  = blockIdx.x;
    int tid = threadIdx.x;
    for (int b = tid; b < NB; b += blockDim.x) {
        base[b] = bucketBase[b] + within[b * NBLK + bk];
        cur[b]  = 0;
    }
    __syncthreads();
    int slice = (n_edges + NBLK - 1) / NBLK;
    int e0 = bk * slice;
    int e1 = min(e0 + slice, n_edges);
    for (int e = e0 + tid; e < e1; e += blockDim.x) {
        int t = dst[e];
        int b = t >> BSH;
        int sl = atomicAdd(&cur[b], 1);
        entries[base[b] + sl] = ((t & 63) << 17) | src[e];   // block-local lines
    }
}

// ---- K4: within-bucket counting sort -> per-node CSR (pack, off) -----------
__global__ void bucket_sort_kernel(const int* __restrict__ entries,
                                   const int* __restrict__ bucketBase,
                                   int* __restrict__ pack,
                                   int* __restrict__ off,
                                   int n_nodes, int NB) {
    __shared__ int cnt[64];
    __shared__ int cur[64];
    int b   = blockIdx.x;
    int tid = threadIdx.x;                        // 256
    int beg = bucketBase[b];
    int end = bucketBase[b + 1];
    if (tid < 64) cnt[tid] = 0;
    __syncthreads();
    for (int j = beg + tid; j < end; j += 256)
        atomicAdd(&cnt[entries[j] >> 17], 1);
    __syncthreads();
    if (tid < 64) {                               // wave 0: scan 64 bins
        int v = cnt[tid];
        int incl = v;
        #pragma unroll
        for (int dd = 1; dd < 64; dd <<= 1) {
            int t = __shfl_up(incl, dd, 64);
            if (tid >= dd) incl += t;
        }
        int excl = incl - v;
        cur[tid] = excl;
        int node = (b << BSH) + tid;
        if (node < n_nodes) off[node] = beg + excl;
    }
    __syncthreads();
    for (int j = beg + tid; j < end; j += 256) {
        int e = entries[j];
        int pos = beg + atomicAdd(&cur[e >> 17], 1);
        pack[pos] = e & 0x1FFFF;                  // writes stay in bucket region
    }
}

// ---- K5: pull-reduce, wave per node, 2x4 edge-slots x float4 ---------------
__global__ void gather_kernel(const float* __restrict__ h,
                              const float2* __restrict__ pairD,
                              const float2* __restrict__ pairS,
                              const int* __restrict__ off,
                              const int* __restrict__ pack,
                              float* __restrict__ z,
                              int n_nodes) {
    int gid  = blockIdx.x * blockDim.x + threadIdx.x;
    int node = gid >> 6;
    int lane = threadIdx.x & 63;
    if (node >= n_nodes) return;

    int slot = lane >> 4;      // 0..3 : which edge of each group of 4
    int quad = lane & 15;      // feature quad: floats [quad*4, quad*4+4)

    int beg = off[node];
    int end = off[node + 1];
    float2 pd = pairD[node];   // (sD+b, d[t]) — wave-uniform

    float4 acc0 = make_float4(0.f, 0.f, 0.f, 0.f);
    float4 acc1 = make_float4(0.f, 0.f, 0.f, 0.f);

    // 8 edges per iteration as two independent dependency chains
    for (int base = beg; base < end; base += 8) {
        int j0 = base + slot;
        int j1 = base + 4 + slot;
        bool v0 = (j0 < end);
        bool v1 = (j1 < end);
        int s0 = v0 ? pack[j0] : 0;
        int s1 = v1 ? pack[j1] : 0;
        float2 ps0 = pairS[s0];
        float2 ps1 = pairS[s1];
        const float4 hv0 = *reinterpret_cast<const float4*>(
            &h[(size_t)s0 * IN_DIM + quad * 4]);
        const float4 hv1 = *reinterpret_cast<const float4*>(
            &h[(size_t)s1 * IN_DIM + quad * 4]);
        float c0 = v0 ? fast_tanh(pd.x + ps0.x) * ps0.y : 0.f;
        float c1 = v1 ? fast_tanh(pd.x + ps1.x) * ps1.y : 0.f;
        acc0.x = fmaf(hv0.x, c0, acc0.x);
        acc0.y = fmaf(hv0.y, c0, acc0.y);
        acc0.z = fmaf(hv0.z, c0, acc0.z);
        acc0.w = fmaf(hv0.w, c0, acc0.w);
        acc1.x = fmaf(hv1.x, c1, acc1.x);
        acc1.y = fmaf(hv1.y, c1, acc1.y);
        acc1.z = fmaf(hv1.z, c1, acc1.z);
        acc1.w = fmaf(hv1.w, c1, acc1.w);
    }

    float4 acc = make_float4(acc0.x + acc1.x, acc0.y + acc1.y,
                             acc0.z + acc1.z, acc0.w + acc1.w);

    acc.x += __shfl_xor(acc.x, 16, 64);
    acc.y += __shfl_xor(acc.y, 16, 64);
    acc.z += __shfl_xor(acc.z, 16, 64);
    acc.w += __shfl_xor(acc.w, 16, 64);
    acc.x += __shfl_xor(acc.x, 32, 64);
    acc.y += __shfl_xor(acc.y, 32, 64);
    acc.z += __shfl_xor(acc.z, 32, 64);
    acc.w += __shfl_xor(acc.w, 32, 64);

    if (slot == 0) {
        acc.x *= pd.y; acc.y *= pd.y; acc.z *= pd.y; acc.w *= pd.y;  // * d[t]
        *reinterpret_cast<float4*>(&z[(size_t)node * IN_DIM + quad * 4]) = acc;
    }
}

// ---- fallback (atomic push) ------------------------------------------------
__global__ void node_scores_kernel(const float* __restrict__ h,
                                   const float* __restrict__ d,
                                   const float* __restrict__ gate_w,
                                   const float* __restrict__ gate_b,
                                   float2* __restrict__ pairD,
                                   float2* __restrict__ pairS,
                                   int n_nodes) {
    int gid  = blockIdx.x * blockDim.x + threadIdx.x;
    int node = gid >> 6;
    int lane = threadIdx.x & 63;
    if (node >= n_nodes) return;
    float hv = h[node * IN_DIM + lane];
    float pd = hv * gate_w[lane];
    float ps = hv * gate_w[IN_DIM + lane];
    #pragma unroll
    for (int off = 32; off > 0; off >>= 1) {
        pd += __shfl_xor(pd, off, 64);
        ps += __shfl_xor(ps, off, 64);
    }
    if (lane == 0) {
        float dv = d[node];
        pairD[node] = make_float2(pd + gate_b[0], dv);
        pairS[node] = make_float2(ps, dv);
    }
}

__global__ void edge_scatter_atomic_kernel(const float* __restrict__ h,
                                           const int* __restrict__ src,
                                           const int* __restrict__ dst,
                                           const float2* __restrict__ pairD,
                                           const float2* __restrict__ pairS,
                                           float* __restrict__ z,
                                           int n_edges) {
    int gid  = blockIdx.x * blockDim.x + threadIdx.x;
    int e    = gid >> 6;
    int lane = threadIdx.x & 63;
    if (e >= n_edges) return;
    int s = src[e];
    int t = dst[e];
    float2 pt = pairD[t];
    float2 ps = pairS[s];
    float c = tanhf(pt.x + ps.x) * pt.y * ps.y;
    atomicAdd(&z[t * IN_DIM + lane], h[s * IN_DIM + lane] * c);
}

extern "C" void kernel_launch(void* const* d_in, const int* in_sizes, int n_in,
                              void* d_out, int out_size, void* d_ws, size_t ws_size,
                              hipStream_t stream) {
    const float* h      = (const float*)d_in[0];
    const float* d      = (const float*)d_in[1];
    const int*   src    = (const int*)d_in[2];
    const int*   dst    = (const int*)d_in[3];
    const float* gate_w = (const float*)d_in[4];
    const float* gate_b = (const float*)d_in[5];

    const int n_nodes = in_sizes[1];
    const int n_edges = in_sizes[2];
    float* z = (float*)d_out;

    const int NB = (n_nodes + 63) >> BSH;   // 64-node buckets (782)

    // ws layout: pairD, pairS, pack, entries, counts, within, btot, bucketBase, off
    size_t need = (size_t)n_nodes * 2 * sizeof(float2)
                + (size_t)n_edges * 2 * sizeof(int)
                + (size_t)(2 * NB * NBLK + 2 * NB + 1 + n_nodes + 1) * sizeof(int);

    if (ws_size < need || NB > 1024 || n_nodes > (1 << 17)) {
        float2* pairD = (float2*)d_ws;
        float2* pairS = pairD + n_nodes;
        hipMemsetAsync(z, 0, (size_t)out_size * sizeof(float), stream);
        {
            int total = n_nodes * 64, threads = 256;
            node_scores_kernel<<<(total + threads - 1) / threads, threads, 0, stream>>>(
                h, d, gate_w, gate_b, pairD, pairS, n_nodes);
        }
        {
            long long total = (long long)n_edges * 64;
            int threads = 256;
            edge_scatter_atomic_kernel<<<(int)((total + threads - 1) / threads), threads, 0, stream>>>(
                h, src, dst, pairD, pairS, z, n_edges);
        }
        return;
    }

    float2* pairD      = (float2*)d_ws;
    float2* pairS      = pairD + n_nodes;
    int*    pack       = (int*)(pairS + n_nodes);   // n_edges
    int*    entries    = pack + n_edges;            // n_edges
    int*    counts     = entries + n_edges;         // [NBLK][NB]
    int*    within     = counts + NBLK * NB;        // [NB][NBLK]
    int*    btot       = within + NB * NBLK;        // NB
    int*    bucketBase = btot + NB;                 // NB+1
    int*    off        = bucketBase + NB + 1;       // n_nodes+1

    const int scoreBlocks = (n_nodes * 64 + 255) / 256;

    // K1: node scores + per-block bucket histogram
    scores_and_count_kernel<<<scoreBlocks + NBLK, 256, NB * sizeof(int), stream>>>(
        h, d, gate_w, gate_b, pairD, pairS, dst, counts,
        n_nodes, n_edges, NB, scoreBlocks);

    // K2: per-bucket scan across blocks
    bucket_block_scan_kernel<<<NB, NBLK, 0, stream>>>(counts, within, btot, NB);

    // K2b: scan bucket totals -> bucketBase; off[n]=n_edges
    bucket_base_scan_kernel<<<1, 1024, 0, stream>>>(
        btot, bucketBase, off, NB, n_nodes, n_edges);

    // K3: place edges into per-(bucket,block) contiguous runs
    bin_place_kernel<<<NBLK, 256, 2 * NB * sizeof(int), stream>>>(
        src, dst, bucketBase, within, entries, n_edges, NB);

    // K4: within-bucket counting sort -> per-node CSR (pack) + off
    bucket_sort_kernel<<<NB, 256, 0, stream>>>(
        entries, bucketBase, pack, off, n_nodes, NB);

    // K5: pull-reduce gather (wave per node), writes z exactly once
    {
        long long total = (long long)n_nodes * 64;
        gather_kernel<<<(int)((total + 255) / 256), 256, 0, stream>>>(
            h, pairD, pairS, off, pack, z, n_nodes);
    }
}

// Round 7
// 85.306 us; speedup vs baseline: 5.7787x; 1.0051x over previous
//
#include <hip/hip_runtime.h>
#include <cmath>

#define IN_DIM 64
#define NBLK   128     // blocks for bin-count / bin-place (must be 128: 2 waves scan)
#define BSH    6       // 64 nodes per bucket

// fast tanh: 1 - 2/(e^{2x}+1); saturates correctly (+inf->1, -inf->-1)
__device__ __forceinline__ float fast_tanh(float x) {
    return 1.0f - __fdividef(2.0f, __expf(2.0f * x) + 1.0f);
}

// ---- K1 fused: node scores (blocks [0,scoreBlocks)) + per-block bucket count
__global__ void scores_and_count_kernel(const float* __restrict__ h,
                                        const float* __restrict__ d,
                                        const float* __restrict__ gate_w,
                                        const float* __restrict__ gate_b,
                                        float2* __restrict__ pairD,
                                        float2* __restrict__ pairS,
                                        const int* __restrict__ dst,
                                        int* __restrict__ counts,   // [NBLK][NB]
                                        int n_nodes, int n_edges, int NB,
                                        int scoreBlocks) {
    extern __shared__ int cnt[];                  // NB ints (count role only)
    if ((int)blockIdx.x < scoreBlocks) {
        int gid  = blockIdx.x * blockDim.x + threadIdx.x;
        int node = gid >> 6;
        int lane = threadIdx.x & 63;
        if (node >= n_nodes) return;
        float hv = h[node * IN_DIM + lane];
        float pd = hv * gate_w[lane];             // w_dst = gate_w[:64]
        float ps = hv * gate_w[IN_DIM + lane];    // w_src = gate_w[64:]
        #pragma unroll
        for (int off = 32; off > 0; off >>= 1) {
            pd += __shfl_xor(pd, off, 64);
            ps += __shfl_xor(ps, off, 64);
        }
        if (lane == 0) {
            float dv = d[node];
            pairD[node] = make_float2(pd + gate_b[0], dv);
            pairS[node] = make_float2(ps, dv);
        }
    } else {
        int bk  = blockIdx.x - scoreBlocks;       // 0..NBLK-1
        int tid = threadIdx.x;
        for (int b = tid; b < NB; b += blockDim.x) cnt[b] = 0;
        __syncthreads();
        int slice = (n_edges + NBLK - 1) / NBLK;
        int e0 = bk * slice;
        int e1 = min(e0 + slice, n_edges);
        for (int e = e0 + tid; e < e1; e += blockDim.x)
            atomicAdd(&cnt[dst[e] >> BSH], 1);
        __syncthreads();
        for (int b = tid; b < NB; b += blockDim.x)
            counts[bk * NB + b] = cnt[b];         // coalesced
    }
}

// ---- K2: per-bucket exclusive scan over the NBLK block counts --------------
__global__ void bucket_block_scan_kernel(const int* __restrict__ counts, // [NBLK][NB]
                                         int* __restrict__ within,      // [NB][NBLK]
                                         int* __restrict__ btot,        // [NB]
                                         int NB) {
    __shared__ int w0sum;
    int b   = blockIdx.x;
    int tid = threadIdx.x;                        // NBLK = 128 threads, 2 waves
    int v = counts[tid * NB + b];                 // strided read, L2-hot
    int incl = v;
    #pragma unroll
    for (int dd = 1; dd < 64; dd <<= 1) {
        int t = __shfl_up(incl, dd, 64);
        if ((tid & 63) >= dd) incl += t;
    }
    if (tid == 63) w0sum = incl;
    __syncthreads();
    if (tid >= 64) incl += w0sum;
    within[b * NBLK + tid] = incl - v;            // exclusive, coalesced write
    if (tid == NBLK - 1) btot[b] = incl;
}

// ---- K2b: single-block exclusive scan of bucket totals ---------------------
__global__ void bucket_base_scan_kernel(const int* __restrict__ btot,
                                        int* __restrict__ bucketBase,  // [NB+1]
                                        int* __restrict__ off,         // [n_nodes+1]
                                        int NB, int n_nodes, int n_edges) {
    __shared__ int wsum[16];
    __shared__ int wpre[16];
    int tid = threadIdx.x;                        // 1024
    int lane = tid & 63, w = tid >> 6;
    int v = (tid < NB) ? btot[tid] : 0;
    int incl = v;
    #pragma unroll
    for (int dd = 1; dd < 64; dd <<= 1) {
        int t = __shfl_up(incl, dd, 64);
        if (lane >= dd) incl += t;
    }
    if (lane == 63) wsum[w] = incl;
    __syncthreads();
    if (tid == 0) {
        int run = 0;
        for (int j = 0; j < 16; ++j) { wpre[j] = run; run += wsum[j]; }
    }
    __syncthreads();
    int excl = incl - v + wpre[w];
    if (tid < NB) bucketBase[tid] = excl;
    if (tid == 0) { bucketBase[NB] = n_edges; off[n_nodes] = n_edges; }
}

// ---- K3: place edges into per-(bucket,block) contiguous runs ---------------
__global__ void bin_place_kernel(const int* __restrict__ src,
                                 const int* __restrict__ dst,
                                 const int* __restrict__ bucketBase,
                                 const int* __restrict__ within,    // [NB][NBLK]
                                 int* __restrict__ entries,
                                 int n_edges, int NB) {
    extern __shared__ int smem[];
    int* base = smem;          // NB
    int* cur  = smem + NB;     // NB
    int bk  = blockIdx.x;
    int tid = threadIdx.x;
    for (int b = tid; b < NB; b += blockDim.x) {
        base[b] = bucketBase[b] + within[b * NBLK + bk];
        cur[b]  = 0;
    }
    __syncthreads();
    int slice = (n_edges + NBLK - 1) / NBLK;
    int e0 = bk * slice;
    int e1 = min(e0 + slice, n_edges);
    for (int e = e0 + tid; e < e1; e += blockDim.x) {
        int t = dst[e];
        int b = t >> BSH;
        int sl = atomicAdd(&cur[b], 1);
        entries[base[b] + sl] = ((t & 63) << 17) | src[e];   // block-local lines
    }
}

// ---- K4: within-bucket counting sort -> per-node CSR with precomputed c ----
// pack2[pos] = (src, c) where c = tanh(sD[t]+sS[s]) * d[s] * d[t]
__global__ void bucket_sort_kernel(const int* __restrict__ entries,
                                   const int* __restrict__ bucketBase,
                                   const float2* __restrict__ pairD,
                                   const float2* __restrict__ pairS,
                                   int2* __restrict__ pack2,
                                   int* __restrict__ off,
                                   int n_nodes, int NB) {
    __shared__ int   cnt[64];
    __shared__ int   cur[64];
    __shared__ float sDl[64];    // sD + b for the bucket's 64 nodes
    __shared__ float dDl[64];    // d[t]
    int b   = blockIdx.x;
    int tid = threadIdx.x;                        // 256
    int beg = bucketBase[b];
    int end = bucketBase[b + 1];
    if (tid < 64) {
        cnt[tid] = 0;
        int node = (b << BSH) + tid;
        float2 pd = (node < n_nodes) ? pairD[node] : make_float2(0.f, 0.f);
        sDl[tid] = pd.x;
        dDl[tid] = pd.y;
    }
    __syncthreads();
    for (int j = beg + tid; j < end; j += 256)
        atomicAdd(&cnt[entries[j] >> 17], 1);
    __syncthreads();
    if (tid < 64) {                               // wave 0: scan 64 bins
        int v = cnt[tid];
        int incl = v;
        #pragma unroll
        for (int dd = 1; dd < 64; dd <<= 1) {
            int t = __shfl_up(incl, dd, 64);
            if (tid >= dd) incl += t;
        }
        int excl = incl - v;
        cur[tid] = excl;
        int node = (b << BSH) + tid;
        if (node < n_nodes) off[node] = beg + excl;
    }
    __syncthreads();
    for (int j = beg + tid; j < end; j += 256) {
        int e  = entries[j];
        int dl = e >> 17;
        int s  = e & 0x1FFFF;
        float2 ps = pairS[s];                     // random 8B, TLP-hidden
        float c = fast_tanh(sDl[dl] + ps.x) * ps.y * dDl[dl];
        int pos = beg + atomicAdd(&cur[dl], 1);
        pack2[pos] = make_int2(s, __float_as_int(c));  // bucket-local write
    }
}

// ---- K5: pull-reduce, wave per node, 4 slots x 4 unroll = 16 edges in flight
__global__ void gather_kernel(const float* __restrict__ h,
                              const int* __restrict__ off,
                              const int2* __restrict__ pack2,
                              float* __restrict__ z,
                              int n_nodes) {
    int gid  = blockIdx.x * blockDim.x + threadIdx.x;
    int node = gid >> 6;
    int lane = threadIdx.x & 63;
    if (node >= n_nodes) return;

    int slot = lane >> 4;      // 0..3 : edge slot within each group of 4
    int quad = lane & 15;      // feature quad: floats [quad*4, quad*4+4)

    int beg = off[node];
    int end = off[node + 1];

    float4 acc0 = make_float4(0.f, 0.f, 0.f, 0.f);
    float4 acc1 = make_float4(0.f, 0.f, 0.f, 0.f);
    float4 acc2 = make_float4(0.f, 0.f, 0.f, 0.f);
    float4 acc3 = make_float4(0.f, 0.f, 0.f, 0.f);

    const int2 zero2 = make_int2(0, 0);
    for (int base = beg; base < end; base += 16) {
        int j0 = base + slot;
        int j1 = base + 4  + slot;
        int j2 = base + 8  + slot;
        int j3 = base + 12 + slot;
        int2 e0 = (j0 < end) ? pack2[j0] : zero2;   // c = 0.0f when invalid
        int2 e1 = (j1 < end) ? pack2[j1] : zero2;
        int2 e2 = (j2 < end) ? pack2[j2] : zero2;
        int2 e3 = (j3 < end) ? pack2[j3] : zero2;
        const float4 hv0 = *reinterpret_cast<const float4*>(
            &h[(size_t)e0.x * IN_DIM + quad * 4]);
        const float4 hv1 = *reinterpret_cast<const float4*>(
            &h[(size_t)e1.x * IN_DIM + quad * 4]);
        const float4 hv2 = *reinterpret_cast<const float4*>(
            &h[(size_t)e2.x * IN_DIM + quad * 4]);
        const float4 hv3 = *reinterpret_cast<const float4*>(
            &h[(size_t)e3.x * IN_DIM + quad * 4]);
        float c0 = __int_as_float(e0.y);
        float c1 = __int_as_float(e1.y);
        float c2 = __int_as_float(e2.y);
        float c3 = __int_as_float(e3.y);
        acc0.x = fmaf(hv0.x, c0, acc0.x);
        acc0.y = fmaf(hv0.y, c0, acc0.y);
        acc0.z = fmaf(hv0.z, c0, acc0.z);
        acc0.w = fmaf(hv0.w, c0, acc0.w);
        acc1.x = fmaf(hv1.x, c1, acc1.x);
        acc1.y = fmaf(hv1.y, c1, acc1.y);
        acc1.z = fmaf(hv1.z, c1, acc1.z);
        acc1.w = fmaf(hv1.w, c1, acc1.w);
        acc2.x = fmaf(hv2.x, c2, acc2.x);
        acc2.y = fmaf(hv2.y, c2, acc2.y);
        acc2.z = fmaf(hv2.z, c2, acc2.z);
        acc2.w = fmaf(hv2.w, c2, acc2.w);
        acc3.x = fmaf(hv3.x, c3, acc3.x);
        acc3.y = fmaf(hv3.y, c3, acc3.y);
        acc3.z = fmaf(hv3.z, c3, acc3.z);
        acc3.w = fmaf(hv3.w, c3, acc3.w);
    }

    float4 acc = make_float4((acc0.x + acc1.x) + (acc2.x + acc3.x),
                             (acc0.y + acc1.y) + (acc2.y + acc3.y),
                             (acc0.z + acc1.z) + (acc2.z + acc3.z),
                             (acc0.w + acc1.w) + (acc2.w + acc3.w));

    acc.x += __shfl_xor(acc.x, 16, 64);
    acc.y += __shfl_xor(acc.y, 16, 64);
    acc.z += __shfl_xor(acc.z, 16, 64);
    acc.w += __shfl_xor(acc.w, 16, 64);
    acc.x += __shfl_xor(acc.x, 32, 64);
    acc.y += __shfl_xor(acc.y, 32, 64);
    acc.z += __shfl_xor(acc.z, 32, 64);
    acc.w += __shfl_xor(acc.w, 32, 64);

    if (slot == 0)
        *reinterpret_cast<float4*>(&z[(size_t)node * IN_DIM + quad * 4]) = acc;
}

// ---- fallback (atomic push) ------------------------------------------------
__global__ void node_scores_kernel(const float* __restrict__ h,
                                   const float* __restrict__ d,
                                   const float* __restrict__ gate_w,
                                   const float* __restrict__ gate_b,
                                   float2* __restrict__ pairD,
                                   float2* __restrict__ pairS,
                                   int n_nodes) {
    int gid  = blockIdx.x * blockDim.x + threadIdx.x;
    int node = gid >> 6;
    int lane = threadIdx.x & 63;
    if (node >= n_nodes) return;
    float hv = h[node * IN_DIM + lane];
    float pd = hv * gate_w[lane];
    float ps = hv * gate_w[IN_DIM + lane];
    #pragma unroll
    for (int off = 32; off > 0; off >>= 1) {
        pd += __shfl_xor(pd, off, 64);
        ps += __shfl_xor(ps, off, 64);
    }
    if (lane == 0) {
        float dv = d[node];
        pairD[node] = make_float2(pd + gate_b[0], dv);
        pairS[node] = make_float2(ps, dv);
    }
}

__global__ void edge_scatter_atomic_kernel(const float* __restrict__ h,
                                           const int* __restrict__ src,
                                           const int* __restrict__ dst,
                                           const float2* __restrict__ pairD,
                                           const float2* __restrict__ pairS,
                                           float* __restrict__ z,
                                           int n_edges) {
    int gid  = blockIdx.x * blockDim.x + threadIdx.x;
    int e    = gid >> 6;
    int lane = threadIdx.x & 63;
    if (e >= n_edges) return;
    int s = src[e];
    int t = dst[e];
    float2 pt = pairD[t];
    float2 ps = pairS[s];
    float c = tanhf(pt.x + ps.x) * pt.y * ps.y;
    atomicAdd(&z[t * IN_DIM + lane], h[s * IN_DIM + lane] * c);
}

extern "C" void kernel_launch(void* const* d_in, const int* in_sizes, int n_in,
                              void* d_out, int out_size, void* d_ws, size_t ws_size,
                              hipStream_t stream) {
    const float* h      = (const float*)d_in[0];
    const float* d      = (const float*)d_in[1];
    const int*   src    = (const int*)d_in[2];
    const int*   dst    = (const int*)d_in[3];
    const float* gate_w = (const float*)d_in[4];
    const float* gate_b = (const float*)d_in[5];

    const int n_nodes = in_sizes[1];
    const int n_edges = in_sizes[2];
    float* z = (float*)d_out;

    const int NB = (n_nodes + 63) >> BSH;   // 64-node buckets (782)

    // ws layout: pairD, pairS, pack2 (int2), entries, counts, within, btot,
    //            bucketBase, off
    size_t need = (size_t)n_nodes * 2 * sizeof(float2)
                + (size_t)n_edges * sizeof(int2)
                + (size_t)n_edges * sizeof(int)
                + (size_t)(2 * NB * NBLK + 2 * NB + 1 + n_nodes + 1) * sizeof(int);

    if (ws_size < need || NB > 1024 || n_nodes > (1 << 17)) {
        float2* pairD = (float2*)d_ws;
        float2* pairS = pairD + n_nodes;
        hipMemsetAsync(z, 0, (size_t)out_size * sizeof(float), stream);
        {
            int total = n_nodes * 64, threads = 256;
            node_scores_kernel<<<(total + threads - 1) / threads, threads, 0, stream>>>(
                h, d, gate_w, gate_b, pairD, pairS, n_nodes);
        }
        {
            long long total = (long long)n_edges * 64;
            int threads = 256;
            edge_scatter_atomic_kernel<<<(int)((total + threads - 1) / threads), threads, 0, stream>>>(
                h, src, dst, pairD, pairS, z, n_edges);
        }
        return;
    }

    float2* pairD      = (float2*)d_ws;
    float2* pairS      = pairD + n_nodes;
    int2*   pack2      = (int2*)(pairS + n_nodes);  // n_edges (8B aligned)
    int*    entries    = (int*)(pack2 + n_edges);   // n_edges
    int*    counts     = entries + n_edges;         // [NBLK][NB]
    int*    within     = counts + NBLK * NB;        // [NB][NBLK]
    int*    btot       = within + NB * NBLK;        // NB
    int*    bucketBase = btot + NB;                 // NB+1
    int*    off        = bucketBase + NB + 1;       // n_nodes+1

    const int scoreBlocks = (n_nodes * 64 + 255) / 256;

    // K1: node scores + per-block bucket histogram
    scores_and_count_kernel<<<scoreBlocks + NBLK, 256, NB * sizeof(int), stream>>>(
        h, d, gate_w, gate_b, pairD, pairS, dst, counts,
        n_nodes, n_edges, NB, scoreBlocks);

    // K2: per-bucket scan across blocks
    bucket_block_scan_kernel<<<NB, NBLK, 0, stream>>>(counts, within, btot, NB);

    // K2b: scan bucket totals -> bucketBase; off[n]=n_edges
    bucket_base_scan_kernel<<<1, 1024, 0, stream>>>(
        btot, bucketBase, off, NB, n_nodes, n_edges);

    // K3: place edges into per-(bucket,block) contiguous runs
    bin_place_kernel<<<NBLK, 256, 2 * NB * sizeof(int), stream>>>(
        src, dst, bucketBase, within, entries, n_edges, NB);

    // K4: within-bucket counting sort -> per-node CSR (src, c) + off
    bucket_sort_kernel<<<NB, 256, 0, stream>>>(
        entries, bucketBase, pairD, pairS, pack2, off, n_nodes, NB);

    // K5: pull-reduce gather (wave per node), writes z exactly once
    {
        long long total = (long long)n_nodes * 64;
        gather_kernel<<<(int)((total + 255) / 256), 256, 0, stream>>>(
            h, off, pack2, z, n_nodes);
    }
}

// Round 8
// 79.233 us; speedup vs baseline: 6.2216x; 1.0766x over previous
//
#include <hip/hip_runtime.h>
#include <hip/hip_fp16.h>
#include <cmath>

#define IN_DIM 64
#define NBLK   128     // blocks for bin-count / bin-place (must be 128: 2 waves scan)
#define BSH    6       // 64 nodes per bucket

// fast tanh: 1 - 2/(e^{2x}+1); saturates correctly (+inf->1, -inf->-1)
__device__ __forceinline__ float fast_tanh(float x) {
    return 1.0f - __fdividef(2.0f, __expf(2.0f * x) + 1.0f);
}

__device__ __forceinline__ float2 half2_to_float2(unsigned int u) {
    __half2 h = *reinterpret_cast<__half2*>(&u);
    return __half22float2(h);
}

// ---- K1 fused: node scores + h->fp16 (blocks [0,scoreBlocks)) + bucket count
__global__ void scores_and_count_kernel(const float* __restrict__ h,
                                        const float* __restrict__ d,
                                        const float* __restrict__ gate_w,
                                        const float* __restrict__ gate_b,
                                        float2* __restrict__ pairD,
                                        float2* __restrict__ pairS,
                                        unsigned short* __restrict__ hh,  // fp16 h
                                        const int* __restrict__ dst,
                                        int* __restrict__ counts,   // [NBLK][NB]
                                        int n_nodes, int n_edges, int NB,
                                        int scoreBlocks) {
    extern __shared__ int cnt[];                  // NB ints (count role only)
    if ((int)blockIdx.x < scoreBlocks) {
        int gid  = blockIdx.x * blockDim.x + threadIdx.x;
        int node = gid >> 6;
        int lane = threadIdx.x & 63;
        if (node >= n_nodes) return;
        float hv = h[node * IN_DIM + lane];
        hh[node * IN_DIM + lane] = __half_as_ushort(__float2half_rn(hv));
        float pd = hv * gate_w[lane];             // w_dst = gate_w[:64]
        float ps = hv * gate_w[IN_DIM + lane];    // w_src = gate_w[64:]
        #pragma unroll
        for (int off = 32; off > 0; off >>= 1) {
            pd += __shfl_xor(pd, off, 64);
            ps += __shfl_xor(ps, off, 64);
        }
        if (lane == 0) {
            float dv = d[node];
            pairD[node] = make_float2(pd + gate_b[0], dv);
            pairS[node] = make_float2(ps, dv);
        }
    } else {
        int bk  = blockIdx.x - scoreBlocks;       // 0..NBLK-1
        int tid = threadIdx.x;
        for (int b = tid; b < NB; b += blockDim.x) cnt[b] = 0;
        __syncthreads();
        int slice = (n_edges + NBLK - 1) / NBLK;
        int e0 = bk * slice;
        int e1 = min(e0 + slice, n_edges);
        for (int e = e0 + tid; e < e1; e += blockDim.x)
            atomicAdd(&cnt[dst[e] >> BSH], 1);
        __syncthreads();
        for (int b = tid; b < NB; b += blockDim.x)
            counts[bk * NB + b] = cnt[b];         // coalesced
    }
}

// ---- K2: per-bucket exclusive scan over the NBLK block counts --------------
__global__ void bucket_block_scan_kernel(const int* __restrict__ counts, // [NBLK][NB]
                                         int* __restrict__ within,      // [NB][NBLK]
                                         int* __restrict__ btot,        // [NB]
                                         int NB) {
    __shared__ int w0sum;
    int b   = blockIdx.x;
    int tid = threadIdx.x;                        // NBLK = 128 threads, 2 waves
    int v = counts[tid * NB + b];                 // strided read, L2-hot
    int incl = v;
    #pragma unroll
    for (int dd = 1; dd < 64; dd <<= 1) {
        int t = __shfl_up(incl, dd, 64);
        if ((tid & 63) >= dd) incl += t;
    }
    if (tid == 63) w0sum = incl;
    __syncthreads();
    if (tid >= 64) incl += w0sum;
    within[b * NBLK + tid] = incl - v;            // exclusive, coalesced write
    if (tid == NBLK - 1) btot[b] = incl;
}

// ---- K2b: single-block exclusive scan of bucket totals ---------------------
__global__ void bucket_base_scan_kernel(const int* __restrict__ btot,
                                        int* __restrict__ bucketBase,  // [NB+1]
                                        int* __restrict__ off,         // [n_nodes+1]
                                        int NB, int n_nodes, int n_edges) {
    __shared__ int wsum[16];
    __shared__ int wpre[16];
    int tid = threadIdx.x;                        // 1024
    int lane = tid & 63, w = tid >> 6;
    int v = (tid < NB) ? btot[tid] : 0;
    int incl = v;
    #pragma unroll
    for (int dd = 1; dd < 64; dd <<= 1) {
        int t = __shfl_up(incl, dd, 64);
        if (lane >= dd) incl += t;
    }
    if (lane == 63) wsum[w] = incl;
    __syncthreads();
    if (tid == 0) {
        int run = 0;
        for (int j = 0; j < 16; ++j) { wpre[j] = run; run += wsum[j]; }
    }
    __syncthreads();
    int excl = incl - v + wpre[w];
    if (tid < NB) bucketBase[tid] = excl;
    if (tid == 0) { bucketBase[NB] = n_edges; off[n_nodes] = n_edges; }
}

// ---- K3: place edges into per-(bucket,block) contiguous runs ---------------
__global__ void bin_place_kernel(const int* __restrict__ src,
                                 const int* __restrict__ dst,
                                 const int* __restrict__ bucketBase,
                                 const int* __restrict__ within,    // [NB][NBLK]
                                 int* __restrict__ entries,
                                 int n_edges, int NB) {
    extern __shared__ int smem[];
    int* base = smem;          // NB
    int* cur  = smem + NB;     // NB
    int bk  = blockIdx.x;
    int tid = threadIdx.x;
    for (int b = tid; b < NB; b += blockDim.x) {
        base[b] = bucketBase[b] + within[b * NBLK + bk];
        cur[b]  = 0;
    }
    __syncthreads();
    int slice = (n_edges + NBLK - 1) / NBLK;
    int e0 = bk * slice;
    int e1 = min(e0 + slice, n_edges);
    for (int e = e0 + tid; e < e1; e += blockDim.x) {
        int t = dst[e];
        int b = t >> BSH;
        int sl = atomicAdd(&cur[b], 1);
        entries[base[b] + sl] = ((t & 63) << 17) | src[e];   // block-local lines
    }
}

// ---- K4: within-bucket counting sort -> per-node CSR with precomputed c ----
// pack2[pos] = (src, c) where c = tanh(sD[t]+sS[s]) * d[s] * d[t]
__global__ void bucket_sort_kernel(const int* __restrict__ entries,
                                   const int* __restrict__ bucketBase,
                                   const float2* __restrict__ pairD,
                                   const float2* __restrict__ pairS,
                                   int2* __restrict__ pack2,
                                   int* __restrict__ off,
                                   int n_nodes, int NB) {
    __shared__ int   cnt[64];
    __shared__ int   cur[64];
    __shared__ float sDl[64];    // sD + b for the bucket's 64 nodes
    __shared__ float dDl[64];    // d[t]
    int b   = blockIdx.x;
    int tid = threadIdx.x;                        // 256
    int beg = bucketBase[b];
    int end = bucketBase[b + 1];
    if (tid < 64) {
        cnt[tid] = 0;
        int node = (b << BSH) + tid;
        float2 pd = (node < n_nodes) ? pairD[node] : make_float2(0.f, 0.f);
        sDl[tid] = pd.x;
        dDl[tid] = pd.y;
    }
    __syncthreads();
    for (int j = beg + tid; j < end; j += 256)
        atomicAdd(&cnt[entries[j] >> 17], 1);
    __syncthreads();
    if (tid < 64) {                               // wave 0: scan 64 bins
        int v = cnt[tid];
        int incl = v;
        #pragma unroll
        for (int dd = 1; dd < 64; dd <<= 1) {
            int t = __shfl_up(incl, dd, 64);
            if (tid >= dd) incl += t;
        }
        int excl = incl - v;
        cur[tid] = excl;
        int node = (b << BSH) + tid;
        if (node < n_nodes) off[node] = beg + excl;
    }
    __syncthreads();
    for (int j = beg + tid; j < end; j += 256) {
        int e  = entries[j];
        int dl = e >> 17;
        int s  = e & 0x1FFFF;
        float2 ps = pairS[s];                     // random 8B, TLP-hidden
        float c = fast_tanh(sDl[dl] + ps.x) * ps.y * dDl[dl];
        int pos = beg + atomicAdd(&cur[dl], 1);
        pack2[pos] = make_int2(s, __float_as_int(c));  // bucket-local write
    }
}

// ---- K5: pull-reduce, wave per node, 8 slots x 8 fp16 feats, 2-deep unroll -
__global__ void gather_kernel(const unsigned short* __restrict__ hh,
                              const int* __restrict__ off,
                              const int2* __restrict__ pack2,
                              float* __restrict__ z,
                              int n_nodes) {
    int gid  = blockIdx.x * blockDim.x + threadIdx.x;
    int node = gid >> 6;
    int lane = threadIdx.x & 63;
    if (node >= n_nodes) return;

    int slot = lane >> 3;      // 0..7 : edge slot
    int oct  = lane & 7;       // features [oct*8, oct*8+8)

    int beg = off[node];
    int end = off[node + 1];

    float a0[8], a1[8];
    #pragma unroll
    for (int k = 0; k < 8; ++k) { a0[k] = 0.f; a1[k] = 0.f; }

    const int2 zero2 = make_int2(0, 0);
    for (int base = beg; base < end; base += 16) {
        int j0 = base + slot;
        int j1 = base + 8 + slot;
        int2 e0 = (j0 < end) ? pack2[j0] : zero2;   // c = 0.0f when invalid
        int2 e1 = (j1 < end) ? pack2[j1] : zero2;
        const uint4 q0 = *reinterpret_cast<const uint4*>(
            &hh[(size_t)e0.x * IN_DIM + oct * 8]);
        const uint4 q1 = *reinterpret_cast<const uint4*>(
            &hh[(size_t)e1.x * IN_DIM + oct * 8]);
        float c0 = __int_as_float(e0.y);
        float c1 = __int_as_float(e1.y);
        float2 f;
        f = half2_to_float2(q0.x); a0[0] = fmaf(f.x, c0, a0[0]); a0[1] = fmaf(f.y, c0, a0[1]);
        f = half2_to_float2(q0.y); a0[2] = fmaf(f.x, c0, a0[2]); a0[3] = fmaf(f.y, c0, a0[3]);
        f = half2_to_float2(q0.z); a0[4] = fmaf(f.x, c0, a0[4]); a0[5] = fmaf(f.y, c0, a0[5]);
        f = half2_to_float2(q0.w); a0[6] = fmaf(f.x, c0, a0[6]); a0[7] = fmaf(f.y, c0, a0[7]);
        f = half2_to_float2(q1.x); a1[0] = fmaf(f.x, c1, a1[0]); a1[1] = fmaf(f.y, c1, a1[1]);
        f = half2_to_float2(q1.y); a1[2] = fmaf(f.x, c1, a1[2]); a1[3] = fmaf(f.y, c1, a1[3]);
        f = half2_to_float2(q1.z); a1[4] = fmaf(f.x, c1, a1[4]); a1[5] = fmaf(f.y, c1, a1[5]);
        f = half2_to_float2(q1.w); a1[6] = fmaf(f.x, c1, a1[6]); a1[7] = fmaf(f.y, c1, a1[7]);
    }

    float a[8];
    #pragma unroll
    for (int k = 0; k < 8; ++k) a[k] = a0[k] + a1[k];

    // reduce across the 8 slots (lane bits 3,4,5)
    #pragma unroll
    for (int m = 8; m < 64; m <<= 1) {
        #pragma unroll
        for (int k = 0; k < 8; ++k) a[k] += __shfl_xor(a[k], m, 64);
    }

    if (slot == 0) {
        float4 lo = make_float4(a[0], a[1], a[2], a[3]);
        float4 hi = make_float4(a[4], a[5], a[6], a[7]);
        *reinterpret_cast<float4*>(&z[(size_t)node * IN_DIM + oct * 8])     = lo;
        *reinterpret_cast<float4*>(&z[(size_t)node * IN_DIM + oct * 8 + 4]) = hi;
    }
}

// ---- fallback (atomic push) ------------------------------------------------
__global__ void node_scores_kernel(const float* __restrict__ h,
                                   const float* __restrict__ d,
                                   const float* __restrict__ gate_w,
                                   const float* __restrict__ gate_b,
                                   float2* __restrict__ pairD,
                                   float2* __restrict__ pairS,
                                   int n_nodes) {
    int gid  = blockIdx.x * blockDim.x + threadIdx.x;
    int node = gid >> 6;
    int lane = threadIdx.x & 63;
    if (node >= n_nodes) return;
    float hv = h[node * IN_DIM + lane];
    float pd = hv * gate_w[lane];
    float ps = hv * gate_w[IN_DIM + lane];
    #pragma unroll
    for (int off = 32; off > 0; off >>= 1) {
        pd += __shfl_xor(pd, off, 64);
        ps += __shfl_xor(ps, off, 64);
    }
    if (lane == 0) {
        float dv = d[node];
        pairD[node] = make_float2(pd + gate_b[0], dv);
        pairS[node] = make_float2(ps, dv);
    }
}

__global__ void edge_scatter_atomic_kernel(const float* __restrict__ h,
                                           const int* __restrict__ src,
                                           const int* __restrict__ dst,
                                           const float2* __restrict__ pairD,
                                           const float2* __restrict__ pairS,
                                           float* __restrict__ z,
                                           int n_edges) {
    int gid  = blockIdx.x * blockDim.x + threadIdx.x;
    int e    = gid >> 6;
    int lane = threadIdx.x & 63;
    if (e >= n_edges) return;
    int s = src[e];
    int t = dst[e];
    float2 pt = pairD[t];
    float2 ps = pairS[s];
    float c = tanhf(pt.x + ps.x) * pt.y * ps.y;
    atomicAdd(&z[t * IN_DIM + lane], h[s * IN_DIM + lane] * c);
}

extern "C" void kernel_launch(void* const* d_in, const int* in_sizes, int n_in,
                              void* d_out, int out_size, void* d_ws, size_t ws_size,
                              hipStream_t stream) {
    const float* h      = (const float*)d_in[0];
    const float* d      = (const float*)d_in[1];
    const int*   src    = (const int*)d_in[2];
    const int*   dst    = (const int*)d_in[3];
    const float* gate_w = (const float*)d_in[4];
    const float* gate_b = (const float*)d_in[5];

    const int n_nodes = in_sizes[1];
    const int n_edges = in_sizes[2];
    float* z = (float*)d_out;

    const int NB = (n_nodes + 63) >> BSH;   // 64-node buckets (782)

    // ws layout: pairD, pairS, hh (fp16 h), pack2 (int2), entries, counts,
    //            within, btot, bucketBase, off
    size_t need = (size_t)n_nodes * 2 * sizeof(float2)
                + (size_t)n_nodes * IN_DIM * sizeof(unsigned short)
                + (size_t)n_edges * sizeof(int2)
                + (size_t)n_edges * sizeof(int)
                + (size_t)(2 * NB * NBLK + 2 * NB + 1 + n_nodes + 1) * sizeof(int);

    if (ws_size < need || NB > 1024 || n_nodes > (1 << 17)) {
        float2* pairD = (float2*)d_ws;
        float2* pairS = pairD + n_nodes;
        hipMemsetAsync(z, 0, (size_t)out_size * sizeof(float), stream);
        {
            int total = n_nodes * 64, threads = 256;
            node_scores_kernel<<<(total + threads - 1) / threads, threads, 0, stream>>>(
                h, d, gate_w, gate_b, pairD, pairS, n_nodes);
        }
        {
            long long total = (long long)n_edges * 64;
            int threads = 256;
            edge_scatter_atomic_kernel<<<(int)((total + threads - 1) / threads), threads, 0, stream>>>(
                h, src, dst, pairD, pairS, z, n_edges);
        }
        return;
    }

    float2*         pairD      = (float2*)d_ws;
    float2*         pairS      = pairD + n_nodes;
    unsigned short* hh         = (unsigned short*)(pairS + n_nodes);
    int2*           pack2      = (int2*)(hh + (size_t)n_nodes * IN_DIM);
    int*            entries    = (int*)(pack2 + n_edges);   // n_edges
    int*            counts     = entries + n_edges;         // [NBLK][NB]
    int*            within     = counts + NBLK * NB;        // [NB][NBLK]
    int*            btot       = within + NB * NBLK;        // NB
    int*            bucketBase = btot + NB;                 // NB+1
    int*            off        = bucketBase + NB + 1;       // n_nodes+1

    const int scoreBlocks = (n_nodes * 64 + 255) / 256;

    // K1: node scores + h->fp16 + per-block bucket histogram
    scores_and_count_kernel<<<scoreBlocks + NBLK, 256, NB * sizeof(int), stream>>>(
        h, d, gate_w, gate_b, pairD, pairS, hh, dst, counts,
        n_nodes, n_edges, NB, scoreBlocks);

    // K2: per-bucket scan across blocks
    bucket_block_scan_kernel<<<NB, NBLK, 0, stream>>>(counts, within, btot, NB);

    // K2b: scan bucket totals -> bucketBase; off[n]=n_edges
    bucket_base_scan_kernel<<<1, 1024, 0, stream>>>(
        btot, bucketBase, off, NB, n_nodes, n_edges);

    // K3: place edges into per-(bucket,block) contiguous runs
    bin_place_kernel<<<NBLK, 256, 2 * NB * sizeof(int), stream>>>(
        src, dst, bucketBase, within, entries, n_edges, NB);

    // K4: within-bucket counting sort -> per-node CSR (src, c) + off
    bucket_sort_kernel<<<NB, 256, 0, stream>>>(
        entries, bucketBase, pairD, pairS, pack2, off, n_nodes, NB);

    // K5: pull-reduce gather (wave per node), fp16 h, writes z exactly once
    {
        long long total = (long long)n_nodes * 64;
        gather_kernel<<<(int)((total + 255) / 256), 256, 0, stream>>>(
            hh, off, pack2, z, n_nodes);
    }
}